// Round 1
// baseline (331.837 us; speedup 1.0000x reference)
//
#include <hip/hip_runtime.h>
#include <math.h>

// Attention: out = softmax((q@Wq+bq)(k@Wk+bk)^T / sqrt(D)) @ (v@Wv+bv)
// B=4, S=2048, D=1024, fp32 in/out.
//
// Round 7: all three GEMMs ported from the m97-style 128^2 2-barrier
// structure (MfmaUtil 24%) to the 8-phase 256^2 deep-pipelined template:
//   - 512 thr / 8 waves (2Mx4N), BM=BN=256, BK=64, per-wave C = 128x64
//   - LDS 128 KiB: 2 K-tile double-buffer, each K-tile = 4 half-tiles
//     (A-khalf0, A-khalf1, B-khalf0, B-khalf1) of [256][32] bf16 = 16 KiB
//   - 4 sub-phases per K-tile, 16 MFMA each; one half-tile prefetch per
//     phase (2x global_load_lds width-16); counted s_waitcnt vmcnt(10)
//     twice per K-tile (never 0 in steady state); s_setprio around MFMA
//   - XOR swizzle slot ^= (row>>1)&3 (pre-swizzled global source +
//     swizzled ds_read) -> conflict-free b128 reads
// Kernels: prep (unchanged) -> proj8 (384 blk) -> scores8 (256) -> pv8 (128)
// Workspace layout unchanged (86.2 MB high-water).

using short8  = __attribute__((ext_vector_type(8))) short;
using floatx4 = __attribute__((ext_vector_type(4))) float;

// round-half-up bf16 (2 VALU; differs from RNE only on exact ties)
__device__ __forceinline__ unsigned short f2bf(float f) {
    union { float f; unsigned u; } x; x.f = f;
    return (unsigned short)((x.u + 0x8000u) >> 16);
}

__device__ __forceinline__ void gload_lds16(const unsigned short* g, unsigned short* l) {
    __builtin_amdgcn_global_load_lds(
        (const __attribute__((address_space(1))) unsigned int*)g,
        (__attribute__((address_space(3))) unsigned int*)l, 16, 0, 0);
}

#define SBAR   __builtin_amdgcn_s_barrier()
#define LGKM0  asm volatile("s_waitcnt lgkmcnt(0)" ::: "memory")
#define VMW(n) asm volatile("s_waitcnt vmcnt(" #n ")" ::: "memory")

// ---------------- prep: qkv conv (blocks 0..24575) + W transpose (24576..27647) ----
__global__ __launch_bounds__(256) void prep(
    const float* __restrict__ q, const float* __restrict__ k, const float* __restrict__ v,
    const float* __restrict__ W0, const float* __restrict__ W1, const float* __restrict__ W2,
    unsigned short* __restrict__ qkvbf, unsigned short* __restrict__ Wt)
{
    __shared__ float tile[32][33];
    const int id = blockIdx.x;
    const int t  = threadIdx.x;
    if (id < 24576) {
        const int z  = id >> 13;
        const int xb = id & 8191;
        const float* x = (z == 0) ? q : (z == 1) ? k : v;
        const size_t i = ((size_t)xb * 256 + t) * 4;
        const float4 a = *(const float4*)(x + i);
        ushort4 p = { f2bf(a.x), f2bf(a.y), f2bf(a.z), f2bf(a.w) };
        *(ushort4*)(qkvbf + (size_t)z * 8192 * 1024 + i) = p;
    } else {
        const int idt = id - 24576;
        const int z  = idt >> 10;
        const int r  = idt & 1023;
        const int bx = (r & 31) * 32;
        const int by = (r >> 5) * 32;
        const float* W = (z == 0) ? W0 : (z == 1) ? W1 : W2;
        unsigned short* o = Wt + (size_t)z * 1024 * 1024;
        const int tx = t & 31;
        const int ty = (t >> 5) * 4;
        #pragma unroll
        for (int rr = 0; rr < 4; ++rr)
            tile[ty + rr][tx] = W[(size_t)(by + ty + rr) * 1024 + bx + tx];
        __syncthreads();
        #pragma unroll
        for (int rr = 0; rr < 4; ++rr)
            o[(size_t)(bx + ty + rr) * 1024 + by + tx] = f2bf(tile[tx][ty + rr]);
    }
}

// ======== 8-phase 256x256 GEMM pipeline (bf16, K multiple of 64) ========
// LDS map (shorts): buf b at b*32768; regions: A-k0 @0, A-k1 @8192,
//   B-k0 @16384, B-k1 @24576; each region [256 rows][32 cols].
// Swizzle: 16B slot s of row r holds global slot s ^ ((r>>1)&3).

#define STAGE_A(bb, ks, tt) do { \
    const unsigned short* s_ = gA + (size_t)srow * lda + (tt) * 64 + (ks) * 32 + scol; \
    unsigned short* d_ = lds + (bb) * 32768 + (ks) * 8192 + t512 * 8; \
    gload_lds16(s_, d_); \
    gload_lds16(s_ + (size_t)128 * lda, d_ + 4096); \
} while (0)

#define STAGE_B(bb, ks, tt) do { \
    const unsigned short* s_ = gB + (size_t)srow * ldb + (tt) * 64 + (ks) * 32 + scol; \
    unsigned short* d_ = lds + (bb) * 32768 + 16384 + (ks) * 8192 + t512 * 8; \
    gload_lds16(s_, d_); \
    gload_lds16(s_ + (size_t)128 * ldb, d_ + 4096); \
} while (0)

#define LDSA(bb, ks, i) (*(const short8*)&lds[(bb) * 32768 + (ks) * 8192 + (arow + (i) * 16) * 32 + rslot])
#define LDSB(bb, ks, j) (*(const short8*)&lds[(bb) * 32768 + 16384 + (ks) * 8192 + (brow + (j) * 16) * 32 + rslot])

#define MFMA16(IB) do { \
    __builtin_amdgcn_s_setprio(1); \
    _Pragma("unroll") \
    for (int i_ = 0; i_ < 4; ++i_) \
        _Pragma("unroll") \
        for (int j_ = 0; j_ < 4; ++j_) \
            acc[(IB) + i_][j_] = __builtin_amdgcn_mfma_f32_16x16x32_bf16( \
                af[i_], bf[j_], acc[(IB) + i_][j_], 0, 0, 0); \
    __builtin_amdgcn_s_setprio(0); \
} while (0)

__device__ __forceinline__ void gemm8ph(
    const unsigned short* __restrict__ gA, int lda,
    const unsigned short* __restrict__ gB, int ldb,
    int nt, unsigned short* lds, floatx4 (&acc)[8][4])
{
    const int t512 = threadIdx.x;
    const int lane = t512 & 63;
    const int wave = t512 >> 6;
    const int wr   = wave >> 2;          // 0..1 (M)
    const int wc   = wave & 3;           // 0..3 (N)
    const int l15  = lane & 15;
    const int quad = lane >> 4;
    const int srow = t512 >> 2;                                  // staging row 0..127
    const int scol = ((t512 & 3) ^ ((t512 >> 3) & 3)) * 8;       // pre-swizzled global slot
    const int rslot = (quad ^ ((l15 >> 1) & 3)) * 8;             // swizzled read slot
    const int arow = wr * 128 + l15;
    const int brow = wc * 64 + l15;

    short8 af[4], bf[4];

    // prologue: issue order = consumption order
    STAGE_B(0, 0, 0); STAGE_A(0, 0, 0); STAGE_B(0, 1, 0); STAGE_A(0, 1, 0);
    STAGE_B(1, 0, 1); STAGE_A(1, 0, 1); STAGE_B(1, 1, 1);
    VMW(10);   // B-k0(0), A-k0(0) landed (5 half-tiles = 10 loads newer)
    SBAR;

    int b = 0;
    for (int t = 0; t < nt; ++t, b ^= 1) {
        // ---- p0: read B-k0 + A-k0[0..3]; stage A-k1(t+1) -> buf b^1
        #pragma unroll
        for (int j = 0; j < 4; ++j) bf[j] = LDSB(b, 0, j);
        #pragma unroll
        for (int i = 0; i < 4; ++i) af[i] = LDSA(b, 0, i);
        if (t + 1 < nt) STAGE_A(b ^ 1, 1, t + 1);
        SBAR; LGKM0;
        MFMA16(0);
        SBAR;
        // ---- p1: read A-k0[4..7]; stage B-k0(t+2) -> buf b
        #pragma unroll
        for (int i = 0; i < 4; ++i) af[i] = LDSA(b, 0, i + 4);
        if (t + 2 < nt) STAGE_B(b, 0, t + 2);
        SBAR; LGKM0;
        MFMA16(4);
        if (t == nt - 1)      VMW(0);    // tail: everything drained
        else if (t == nt - 2) VMW(8);    // guards B-k1(t), A-k1(t)
        else                  VMW(10);
        SBAR;
        // ---- p2: read B-k1 + A-k1[0..3]; stage A-k0(t+2) -> buf b
        #pragma unroll
        for (int j = 0; j < 4; ++j) bf[j] = LDSB(b, 1, j);
        #pragma unroll
        for (int i = 0; i < 4; ++i) af[i] = LDSA(b, 1, i);
        if (t + 2 < nt) STAGE_A(b, 0, t + 2);
        SBAR; LGKM0;
        MFMA16(0);
        SBAR;
        // ---- p3: read A-k1[4..7]; stage B-k1(t+2) -> buf b
        #pragma unroll
        for (int i = 0; i < 4; ++i) af[i] = LDSA(b, 1, i + 4);
        if (t + 2 < nt) STAGE_B(b, 1, t + 2);
        SBAR; LGKM0;
        MFMA16(4);
        if (t + 1 < nt) {
            if (t + 1 == nt - 1) VMW(4);   // guards B-k0(t+1), A-k0(t+1)
            else                 VMW(10);
            SBAR;
        }
    }
}

#define EPI_IDS                                   \
    const int tt   = threadIdx.x;                 \
    const int lane = tt & 63;                     \
    const int wave = tt >> 6;                     \
    const int wr   = wave >> 2;                   \
    const int wc   = wave & 3;                    \
    const int l15  = lane & 15;                   \
    const int quad = lane >> 4;

// ---------------- fused QKV projection, 384 blocks, XCD-swizzled ----
__global__ __launch_bounds__(512, 2) void proj8(
    const unsigned short* __restrict__ Abf,
    const unsigned short* __restrict__ Wt,
    const float* __restrict__ bq, const float* __restrict__ bk, const float* __restrict__ bv,
    unsigned short* __restrict__ Qp, unsigned short* __restrict__ Kp,
    unsigned short* __restrict__ Vpt)
{
    __shared__ __attribute__((aligned(16))) unsigned short lds[65536];
    const int id = blockIdx.x;
    const int g  = (id & 7) * 48 + (id >> 3);    // 384 = 8 XCDs x 48
    const int z  = g >> 7;                       // 0..2
    const int r  = g & 127;
    const int m0 = (r >> 2) * 256;
    const int n0 = (r & 3) * 256;

    const unsigned short* gA = Abf + (size_t)z * 8192 * 1024 + (size_t)m0 * 1024;
    const unsigned short* gB = Wt  + (size_t)z * 1024 * 1024 + (size_t)n0 * 1024;

    floatx4 acc[8][4] = {};
    gemm8ph(gA, 1024, gB, 1024, 16, lds, acc);

    EPI_IDS
    const float* bias = (z == 0) ? bq : (z == 1) ? bk : bv;
    #pragma unroll
    for (int j = 0; j < 4; ++j) {
        const int col = n0 + wc * 64 + j * 16 + l15;
        const float bv_ = bias[col];
        #pragma unroll
        for (int i = 0; i < 8; ++i) {
            const int row = m0 + wr * 128 + i * 16 + quad * 4;
            if (z < 2) {
                unsigned short* C = (z == 0) ? Qp : Kp;
                #pragma unroll
                for (int r2 = 0; r2 < 4; ++r2)
                    C[(size_t)(row + r2) * 1024 + col] = f2bf(acc[i][j][r2] + bv_);
            } else {
                ushort4 p = { f2bf(acc[i][j][0] + bv_), f2bf(acc[i][j][1] + bv_),
                              f2bf(acc[i][j][2] + bv_), f2bf(acc[i][j][3] + bv_) };
                *(ushort4*)&Vpt[(size_t)col * 8192 + row] = p;
            }
        }
    }
}

// ---------------- scores: Pexp = exp(Qp @ Kp^T / 32) bf16 + row sums ----
__global__ __launch_bounds__(512, 2) void scores8(
    const unsigned short* __restrict__ Qp,
    const unsigned short* __restrict__ Kp,
    unsigned short* __restrict__ Pexp,
    float* __restrict__ rowsum)
{
    __shared__ __attribute__((aligned(16))) unsigned short lds[65536];
    const int id = blockIdx.x;
    const int g  = (id & 7) * 32 + (id >> 3);    // 256 blocks
    const int z  = g >> 6;
    const int r  = g & 63;
    const int m0 = (r >> 3) * 256;
    const int n0 = (r & 7) * 256;

    const unsigned short* gA = Qp + (size_t)z * 2048 * 1024 + (size_t)m0 * 1024;
    const unsigned short* gB = Kp + (size_t)z * 2048 * 1024 + (size_t)n0 * 1024;

    floatx4 acc[8][4] = {};
    gemm8ph(gA, 1024, gB, 1024, 16, lds, acc);

    EPI_IDS
    unsigned short* P = Pexp + (size_t)z * 2048 * 2048;
    float* rs = rowsum + (size_t)z * 2048;
    #pragma unroll
    for (int i = 0; i < 8; ++i) {
        const int rowb = m0 + wr * 128 + i * 16 + quad * 4;
        float sm[4] = {0.f, 0.f, 0.f, 0.f};
        #pragma unroll
        for (int j = 0; j < 4; ++j) {
            const int col = n0 + wc * 64 + j * 16 + l15;
            #pragma unroll
            for (int r2 = 0; r2 < 4; ++r2) {
                const float p = __expf(acc[i][j][r2] * 0.03125f);
                sm[r2] += p;
                P[(size_t)(rowb + r2) * 2048 + col] = f2bf(p);
            }
        }
        #pragma unroll
        for (int r2 = 0; r2 < 4; ++r2) {
            float s = sm[r2];
            s += __shfl_xor(s, 1);
            s += __shfl_xor(s, 2);
            s += __shfl_xor(s, 4);
            s += __shfl_xor(s, 8);
            if (l15 == 0)
                atomicAdd(&rs[rowb + r2], s);
        }
    }
}

// ---------------- PV: out = (Pexp @ Vpt^T) / rowsum, fp32 ----------------
__global__ __launch_bounds__(512, 2) void pv8(
    const unsigned short* __restrict__ Pexp,
    const unsigned short* __restrict__ Vpt,
    const float* __restrict__ rowsum,
    float* __restrict__ out)
{
    __shared__ __attribute__((aligned(16))) unsigned short lds[65536];
    const int id = blockIdx.x;
    const int g  = (id & 7) * 16 + (id >> 3);    // 128 blocks
    const int z  = g >> 5;
    const int r  = g & 31;
    const int m0 = (r >> 2) * 256;
    const int n0 = (r & 3) * 256;

    const unsigned short* gA = Pexp + (size_t)z * 2048 * 2048 + (size_t)m0 * 2048;
    const unsigned short* gB = Vpt  + (size_t)n0 * 8192 + (size_t)z * 2048;

    floatx4 acc[8][4] = {};
    gemm8ph(gA, 2048, gB, 8192, 32, lds, acc);

    EPI_IDS
    const float* rs = rowsum + (size_t)z * 2048;
    float* C = out + (size_t)z * 2048 * 1024;
    #pragma unroll
    for (int i = 0; i < 8; ++i) {
        const int rowb = m0 + wr * 128 + i * 16 + quad * 4;
        float inv[4];
        #pragma unroll
        for (int r2 = 0; r2 < 4; ++r2) inv[r2] = 1.0f / rs[rowb + r2];
        #pragma unroll
        for (int j = 0; j < 4; ++j) {
            const int col = n0 + wc * 64 + j * 16 + l15;
            #pragma unroll
            for (int r2 = 0; r2 < 4; ++r2)
                C[(size_t)(rowb + r2) * 1024 + col] = acc[i][j][r2] * inv[r2];
        }
    }
}

extern "C" void kernel_launch(void* const* d_in, const int* in_sizes, int n_in,
                              void* d_out, int out_size, void* d_ws, size_t ws_size,
                              hipStream_t stream)
{
    const float* q  = (const float*)d_in[0];
    const float* k  = (const float*)d_in[1];
    const float* v  = (const float*)d_in[2];
    const float* Wq = (const float*)d_in[3];
    const float* bq = (const float*)d_in[4];
    const float* Wk = (const float*)d_in[5];
    const float* bk = (const float*)d_in[6];
    const float* Wv = (const float*)d_in[7];
    const float* bv = (const float*)d_in[8];
    float* out = (float*)d_out;

    const int Bn = 4, S = 2048;

    char* w = (char*)d_ws;
    unsigned short* Wt     = (unsigned short*)(w);                  // 6 MB
    unsigned short* Qp     = (unsigned short*)(w + (6u << 20));     // 16 MB [8192,1024]
    unsigned short* Kp     = (unsigned short*)(w + (22u << 20));    // 16 MB
    unsigned short* Vpt    = (unsigned short*)(w + (38u << 20));    // 16 MB [1024,8192]
    unsigned short* qkvbf  = (unsigned short*)(w + (54u << 20));    // 48 MB (dead after proj)
    unsigned short* Pexp   = (unsigned short*)(w + (54u << 20));    // 32 MB (over dead qkvbf)
    float*          rowsum = (float*)(w + (86u << 20));             // 32 KB

    // zero the row-sum accumulators (ws is poisoned before each call)
    hipMemsetAsync(rowsum, 0, (size_t)Bn * S * sizeof(float), stream);

    // prep: qkv fp32->bf16 + W->W^T bf16
    prep<<<dim3(27648), dim3(256), 0, stream>>>(q, k, v, Wq, Wk, Wv, qkvbf, Wt);

    // fused projections (8-phase 256^2): -> Qp, Kp, Vpt^T
    proj8<<<dim3(384), dim3(512), 0, stream>>>(qkvbf, Wt, bq, bk, bv, Qp, Kp, Vpt);

    // Pexp = exp(Qp @ Kp^T / 32) bf16 + rowsum atomics
    scores8<<<dim3(256), dim3(512), 0, stream>>>(Qp, Kp, Pexp, rowsum);

    // out = (Pexp @ Vpt^T) / rowsum
    pv8<<<dim3(128), dim3(512), 0, stream>>>(Pexp, Vpt, rowsum, out);
}

// Round 2
// 310.154 us; speedup vs baseline: 1.0699x; 1.0699x over previous
//
#include <hip/hip_runtime.h>
#include <math.h>

// Attention: out = softmax((q@Wq+bq)(k@Wk+bk)^T / sqrt(D)) @ (v@Wv+bv)
// B=4, S=2048, D=1024, fp32 in/out.
//
// Round 8: unified 2-phase 128x256 deep-pipelined GEMM (MREP=4).
// Round-7 post-mortem: 256^2 tile + __launch_bounds__(512,2) spilled
// (VGPR_Count=108 < 128 needed by acc alone; +32MB scratch WRITE traffic),
// and grids (384/256/128 at 1 block/CU) left 25-50% of CUs idle.
// Fixes:
//   - tile 128(M)x256(N), 8 waves (2Mx4N), per-wave 64x64, acc[4][4]
//     (64 VGPRs) -> no spill; __launch_bounds__(512) uncapped
//   - grids: proj 768 = 3.0 x 256CU, scores 512 = 2.0x, pv 256 = 1.0x
//   - LDS 96KB: 2 K-tile bufs x {A[128][32], B[256][32]} x 2 K-halves
//   - 2 phases/K-tile, 16 MFMA + 8 ds_read_b128 + 3 global_load_lds each;
//     counted vmcnt(6) steady state (ledger below), setprio around MFMA
//   - XOR swizzle slot ^= (row>>1)&3 (0 bank conflicts, verified r7)
// vmcnt ledger (3 loads per staged group; groups in issue order):
//   prologue: A0B0(0) A1B1(0) A0B0(1) -> vmcnt(6) guards A0B0(0)
//   p0(t) stages A1B1(t+1) [into buf t+1 mod 2, regions dead since p1(t-1)]
//   p1(t) stages A0B0(t+2) [into buf t mod 2, regions dead since p0(t)]
//   end-p0(t): guard A1B1(t) (staged p0(t-1)): newer = 6 if t<nt-1 else 0
//   end-p1(t): guard A0B0(t+1) (staged p1(t-1)): newer = 6 if t+2<nt,
//              3 if t==nt-2, loop exits at t==nt-1 (all drained by VMW(0))
// Kernels: prep (unchanged) -> proj8 (768 blk) -> scores8 (512) -> pv8 (256)
// Workspace layout unchanged (86.2 MB high-water).

using short8  = __attribute__((ext_vector_type(8))) short;
using floatx4 = __attribute__((ext_vector_type(4))) float;

// round-half-up bf16 (2 VALU; differs from RNE only on exact ties)
__device__ __forceinline__ unsigned short f2bf(float f) {
    union { float f; unsigned u; } x; x.f = f;
    return (unsigned short)((x.u + 0x8000u) >> 16);
}

__device__ __forceinline__ void gload_lds16(const unsigned short* g, unsigned short* l) {
    __builtin_amdgcn_global_load_lds(
        (const __attribute__((address_space(1))) unsigned int*)g,
        (__attribute__((address_space(3))) unsigned int*)l, 16, 0, 0);
}

#define SBAR   __builtin_amdgcn_s_barrier()
#define LGKM0  asm volatile("s_waitcnt lgkmcnt(0)" ::: "memory")
#define VMW(n) asm volatile("s_waitcnt vmcnt(" #n ")" ::: "memory")

// ---------------- prep: qkv conv (blocks 0..24575) + W transpose (24576..27647) ----
__global__ __launch_bounds__(256) void prep(
    const float* __restrict__ q, const float* __restrict__ k, const float* __restrict__ v,
    const float* __restrict__ W0, const float* __restrict__ W1, const float* __restrict__ W2,
    unsigned short* __restrict__ qkvbf, unsigned short* __restrict__ Wt)
{
    __shared__ float tile[32][33];
    const int id = blockIdx.x;
    const int t  = threadIdx.x;
    if (id < 24576) {
        const int z  = id >> 13;
        const int xb = id & 8191;
        const float* x = (z == 0) ? q : (z == 1) ? k : v;
        const size_t i = ((size_t)xb * 256 + t) * 4;
        const float4 a = *(const float4*)(x + i);
        ushort4 p = { f2bf(a.x), f2bf(a.y), f2bf(a.z), f2bf(a.w) };
        *(ushort4*)(qkvbf + (size_t)z * 8192 * 1024 + i) = p;
    } else {
        const int idt = id - 24576;
        const int z  = idt >> 10;
        const int r  = idt & 1023;
        const int bx = (r & 31) * 32;
        const int by = (r >> 5) * 32;
        const float* W = (z == 0) ? W0 : (z == 1) ? W1 : W2;
        unsigned short* o = Wt + (size_t)z * 1024 * 1024;
        const int tx = t & 31;
        const int ty = (t >> 5) * 4;
        #pragma unroll
        for (int rr = 0; rr < 4; ++rr)
            tile[ty + rr][tx] = W[(size_t)(by + ty + rr) * 1024 + bx + tx];
        __syncthreads();
        #pragma unroll
        for (int rr = 0; rr < 4; ++rr)
            o[(size_t)(bx + ty + rr) * 1024 + by + tx] = f2bf(tile[tx][ty + rr]);
    }
}

// ======== 2-phase 128x256 GEMM pipeline (bf16, K multiple of 64) ========
// LDS map (shorts): buf b at b*24576; A-kh at kh*4096 [128][32];
//   B-kh at 8192 + kh*8192 [256][32]. Swizzle: 16B slot s of row r holds
//   global slot s ^ ((r>>1)&3).

#define STAGE_A(bb, kh, tt) do { \
    gload_lds16(gA + (size_t)srowA * lda + (tt) * 64 + (kh) * 32 + scol, \
                lds + (bb) * 24576 + (kh) * 4096 + t512 * 8); \
} while (0)

#define STAGE_B(bb, kh, tt) do { \
    const unsigned short* s_ = gB + (size_t)srowA * ldb + (tt) * 64 + (kh) * 32 + scol; \
    unsigned short* d_ = lds + (bb) * 24576 + 8192 + (kh) * 8192 + t512 * 8; \
    gload_lds16(s_, d_); \
    gload_lds16(s_ + (size_t)128 * ldb, d_ + 4096); \
} while (0)

#define LDSA(bb, kh, i) (*(const short8*)&lds[(bb) * 24576 + (kh) * 4096 + (arow + (i) * 16) * 32 + rslot])
#define LDSB(bb, kh, j) (*(const short8*)&lds[(bb) * 24576 + 8192 + (kh) * 8192 + (brow + (j) * 16) * 32 + rslot])

#define MFMA16 do { \
    __builtin_amdgcn_s_setprio(1); \
    _Pragma("unroll") \
    for (int i_ = 0; i_ < 4; ++i_) \
        _Pragma("unroll") \
        for (int j_ = 0; j_ < 4; ++j_) \
            acc[i_][j_] = __builtin_amdgcn_mfma_f32_16x16x32_bf16( \
                af[i_], bf[j_], acc[i_][j_], 0, 0, 0); \
    __builtin_amdgcn_s_setprio(0); \
} while (0)

__device__ __forceinline__ void gemm2ph(
    const unsigned short* __restrict__ gA, int lda,
    const unsigned short* __restrict__ gB, int ldb,
    int nt, unsigned short* lds, floatx4 (&acc)[4][4])
{
    const int t512 = threadIdx.x;
    const int lane = t512 & 63;
    const int wave = t512 >> 6;
    const int wr   = wave >> 2;          // 0..1 (M)
    const int wc   = wave & 3;           // 0..3 (N)
    const int l15  = lane & 15;
    const int quad = lane >> 4;
    const int srowA = t512 >> 2;                                 // staging row 0..127
    const int scol  = ((t512 & 3) ^ ((t512 >> 3) & 3)) * 8;      // pre-swizzled global slot
    const int rslot = (quad ^ ((l15 >> 1) & 3)) * 8;             // swizzled read slot
    const int arow  = wr * 64 + l15;
    const int brow  = wc * 64 + l15;

    short8 af[4], bf[4];

    // prologue (see ledger in header comment)
    STAGE_A(0, 0, 0); STAGE_B(0, 0, 0);
    STAGE_A(0, 1, 0); STAGE_B(0, 1, 0);
    STAGE_A(1, 0, 1); STAGE_B(1, 0, 1);
    VMW(6);
    SBAR;

    int b = 0;
    for (int t = 0; t < nt; ++t, b ^= 1) {
        // ---- p0: consume A-k0,B-k0 of buf b; stage A1B1(t+1) -> buf b^1
        #pragma unroll
        for (int j = 0; j < 4; ++j) bf[j] = LDSB(b, 0, j);
        #pragma unroll
        for (int i = 0; i < 4; ++i) af[i] = LDSA(b, 0, i);
        if (t + 1 < nt) { STAGE_A(b ^ 1, 1, t + 1); STAGE_B(b ^ 1, 1, t + 1); }
        SBAR; LGKM0;
        MFMA16;
        if (t < nt - 1) VMW(6); else VMW(0);
        SBAR;
        // ---- p1: consume A-k1,B-k1 of buf b; stage A0B0(t+2) -> buf b
        #pragma unroll
        for (int j = 0; j < 4; ++j) bf[j] = LDSB(b, 1, j);
        #pragma unroll
        for (int i = 0; i < 4; ++i) af[i] = LDSA(b, 1, i);
        if (t + 2 < nt) { STAGE_A(b, 0, t + 2); STAGE_B(b, 0, t + 2); }
        SBAR; LGKM0;
        MFMA16;
        if (t < nt - 1) {
            if (t + 2 < nt) VMW(6); else VMW(3);
            SBAR;
        }
    }
}

#define EPI_IDS                                   \
    const int tt   = threadIdx.x;                 \
    const int lane = tt & 63;                     \
    const int wave = tt >> 6;                     \
    const int wr   = wave >> 2;                   \
    const int wc   = wave & 3;                    \
    const int l15  = lane & 15;                   \
    const int quad = lane >> 4;

// ---------------- fused QKV projection, 768 blocks, XCD-swizzled ----
__global__ __launch_bounds__(512) void proj8(
    const unsigned short* __restrict__ Abf,
    const unsigned short* __restrict__ Wt,
    const float* __restrict__ bq, const float* __restrict__ bk, const float* __restrict__ bv,
    unsigned short* __restrict__ Qp, unsigned short* __restrict__ Kp,
    unsigned short* __restrict__ Vpt)
{
    __shared__ __attribute__((aligned(16))) unsigned short lds[49152];
    const int id = blockIdx.x;
    const int g  = (id & 7) * 96 + (id >> 3);    // 768 = 8 XCDs x 96
    const int z  = g >> 8;                       // 0..2
    const int r  = g & 255;
    const int m0 = (r >> 2) * 128;
    const int n0 = (r & 3) * 256;

    const unsigned short* gA = Abf + (size_t)z * 8192 * 1024 + (size_t)m0 * 1024;
    const unsigned short* gB = Wt  + (size_t)z * 1024 * 1024 + (size_t)n0 * 1024;

    floatx4 acc[4][4] = {};
    gemm2ph(gA, 1024, gB, 1024, 16, lds, acc);

    EPI_IDS
    const float* bias = (z == 0) ? bq : (z == 1) ? bk : bv;
    #pragma unroll
    for (int j = 0; j < 4; ++j) {
        const int col = n0 + wc * 64 + j * 16 + l15;
        const float bv_ = bias[col];
        #pragma unroll
        for (int i = 0; i < 4; ++i) {
            const int row = m0 + wr * 64 + i * 16 + quad * 4;
            if (z < 2) {
                unsigned short* C = (z == 0) ? Qp : Kp;
                #pragma unroll
                for (int r2 = 0; r2 < 4; ++r2)
                    C[(size_t)(row + r2) * 1024 + col] = f2bf(acc[i][j][r2] + bv_);
            } else {
                ushort4 p = { f2bf(acc[i][j][0] + bv_), f2bf(acc[i][j][1] + bv_),
                              f2bf(acc[i][j][2] + bv_), f2bf(acc[i][j][3] + bv_) };
                *(ushort4*)&Vpt[(size_t)col * 8192 + row] = p;
            }
        }
    }
}

// ---------------- scores: Pexp = exp(Qp @ Kp^T / 32) bf16 + row sums ----
__global__ __launch_bounds__(512) void scores8(
    const unsigned short* __restrict__ Qp,
    const unsigned short* __restrict__ Kp,
    unsigned short* __restrict__ Pexp,
    float* __restrict__ rowsum)
{
    __shared__ __attribute__((aligned(16))) unsigned short lds[49152];
    const int id = blockIdx.x;
    const int g  = (id & 7) * 64 + (id >> 3);    // 512 blocks
    const int z  = g >> 7;
    const int r  = g & 127;
    const int m0 = (r >> 3) * 128;
    const int n0 = (r & 7) * 256;

    const unsigned short* gA = Qp + (size_t)z * 2048 * 1024 + (size_t)m0 * 1024;
    const unsigned short* gB = Kp + (size_t)z * 2048 * 1024 + (size_t)n0 * 1024;

    floatx4 acc[4][4] = {};
    gemm2ph(gA, 1024, gB, 1024, 16, lds, acc);

    EPI_IDS
    unsigned short* P = Pexp + (size_t)z * 2048 * 2048;
    float* rs = rowsum + (size_t)z * 2048;
    #pragma unroll
    for (int i = 0; i < 4; ++i) {
        const int rowb = m0 + wr * 64 + i * 16 + quad * 4;
        float sm[4] = {0.f, 0.f, 0.f, 0.f};
        #pragma unroll
        for (int j = 0; j < 4; ++j) {
            const int col = n0 + wc * 64 + j * 16 + l15;
            #pragma unroll
            for (int r2 = 0; r2 < 4; ++r2) {
                const float p = __expf(acc[i][j][r2] * 0.03125f);
                sm[r2] += p;
                P[(size_t)(rowb + r2) * 2048 + col] = f2bf(p);
            }
        }
        #pragma unroll
        for (int r2 = 0; r2 < 4; ++r2) {
            float s = sm[r2];
            s += __shfl_xor(s, 1);
            s += __shfl_xor(s, 2);
            s += __shfl_xor(s, 4);
            s += __shfl_xor(s, 8);
            if (l15 == 0)
                atomicAdd(&rs[rowb + r2], s);
        }
    }
}

// ---------------- PV: out = (Pexp @ Vpt^T) / rowsum, fp32 ----------------
__global__ __launch_bounds__(512) void pv8(
    const unsigned short* __restrict__ Pexp,
    const unsigned short* __restrict__ Vpt,
    const float* __restrict__ rowsum,
    float* __restrict__ out)
{
    __shared__ __attribute__((aligned(16))) unsigned short lds[49152];
    const int id = blockIdx.x;
    const int g  = (id & 7) * 32 + (id >> 3);    // 256 blocks
    const int z  = g >> 6;
    const int r  = g & 63;
    const int m0 = (r >> 2) * 128;
    const int n0 = (r & 3) * 256;

    const unsigned short* gA = Pexp + (size_t)z * 2048 * 2048 + (size_t)m0 * 2048;
    const unsigned short* gB = Vpt  + (size_t)n0 * 8192 + (size_t)z * 2048;

    floatx4 acc[4][4] = {};
    gemm2ph(gA, 2048, gB, 8192, 32, lds, acc);

    EPI_IDS
    const float* rs = rowsum + (size_t)z * 2048;
    float* C = out + (size_t)z * 2048 * 1024;
    #pragma unroll
    for (int i = 0; i < 4; ++i) {
        const int rowb = m0 + wr * 64 + i * 16 + quad * 4;
        float inv[4];
        #pragma unroll
        for (int r2 = 0; r2 < 4; ++r2) inv[r2] = 1.0f / rs[rowb + r2];
        #pragma unroll
        for (int j = 0; j < 4; ++j) {
            const int col = n0 + wc * 64 + j * 16 + l15;
            #pragma unroll
            for (int r2 = 0; r2 < 4; ++r2)
                C[(size_t)(rowb + r2) * 1024 + col] = acc[i][j][r2] * inv[r2];
        }
    }
}

extern "C" void kernel_launch(void* const* d_in, const int* in_sizes, int n_in,
                              void* d_out, int out_size, void* d_ws, size_t ws_size,
                              hipStream_t stream)
{
    const float* q  = (const float*)d_in[0];
    const float* k  = (const float*)d_in[1];
    const float* v  = (const float*)d_in[2];
    const float* Wq = (const float*)d_in[3];
    const float* bq = (const float*)d_in[4];
    const float* Wk = (const float*)d_in[5];
    const float* bk = (const float*)d_in[6];
    const float* Wv = (const float*)d_in[7];
    const float* bv = (const float*)d_in[8];
    float* out = (float*)d_out;

    const int Bn = 4, S = 2048;

    char* w = (char*)d_ws;
    unsigned short* Wt     = (unsigned short*)(w);                  // 6 MB
    unsigned short* Qp     = (unsigned short*)(w + (6u << 20));     // 16 MB [8192,1024]
    unsigned short* Kp     = (unsigned short*)(w + (22u << 20));    // 16 MB
    unsigned short* Vpt    = (unsigned short*)(w + (38u << 20));    // 16 MB [1024,8192]
    unsigned short* qkvbf  = (unsigned short*)(w + (54u << 20));    // 48 MB (dead after proj)
    unsigned short* Pexp   = (unsigned short*)(w + (54u << 20));    // 32 MB (over dead qkvbf)
    float*          rowsum = (float*)(w + (86u << 20));             // 32 KB

    // zero the row-sum accumulators (ws is poisoned before each call)
    hipMemsetAsync(rowsum, 0, (size_t)Bn * S * sizeof(float), stream);

    // prep: qkv fp32->bf16 + W->W^T bf16
    prep<<<dim3(27648), dim3(256), 0, stream>>>(q, k, v, Wq, Wk, Wv, qkvbf, Wt);

    // fused projections (2-phase 128x256): -> Qp, Kp, Vpt^T
    proj8<<<dim3(768), dim3(512), 0, stream>>>(qkvbf, Wt, bq, bk, bv, Qp, Kp, Vpt);

    // Pexp = exp(Qp @ Kp^T / 32) bf16 + rowsum atomics
    scores8<<<dim3(512), dim3(512), 0, stream>>>(Qp, Kp, Pexp, rowsum);

    // out = (Pexp @ Vpt^T) / rowsum
    pv8<<<dim3(256), dim3(512), 0, stream>>>(Pexp, Vpt, rowsum, out);
}

// Round 3
// 302.778 us; speedup vs baseline: 1.0960x; 1.0244x over previous
//
#include <hip/hip_runtime.h>
#include <math.h>

// Attention: out = softmax((q@Wq+bq)(k@Wk+bk)^T / sqrt(D)) @ (v@Wv+bv)
// B=4, S=2048, D=1024, fp32 in/out.
//
// Round 9: triple-buffered LDS, prefetch distance 2 K-tiles (4 phases).
// Round-8 post-mortem: spill fixed (WRITE back to 49.5MB) but MfmaUtil
// stuck at 29%; per-phase time ~1700cyc vs ~154cyc MFMA + ~256cyc LDS ->
// waves stall on VMW: r8 staged groups only 2 phases (~300-600cyc) before
// their guard, vs ~200-900cyc load latency. Fix: 3 LDS buffers (144KB),
// stage G(t+2) at phase(t) -> 4-phase distance, steady-state vmcnt(9).
// vmcnt ledger (3 loads/group; issue order G0(0) G1(0) G0(1) G1(1) then
// G0(t+2)@p0(t), G1(t+2)@p1(t)):
//   pre-loop guard G0(0): 9 newer -> VMW(9)
//   end-p0(t) guard G1(t) [staged p1(t-2)]: newer = G0(t+1),G1(t+1),G0(t+2)
//     -> 9 if t<nt-2, 6 if t==nt-2, 0 if t==nt-1
//   end-p1(t) guard G0(t+1) [staged p0(t-1)], only if t+1<nt:
//     newer = G1(t+1),G0(t+2),G1(t+2) -> 9 if t<nt-2, 3 if t==nt-2
// Buffer hazard: stage target region last consumed 1 iteration earlier,
// >=2 barriers + consumer lgkmcnt(0) before stage issue -> safe.
// Everything else unchanged from r8 (128x256 tile, acc[4][4], swizzle,
// grids 768/512/256, epilogues).

using short8  = __attribute__((ext_vector_type(8))) short;
using floatx4 = __attribute__((ext_vector_type(4))) float;

// round-half-up bf16 (2 VALU; differs from RNE only on exact ties)
__device__ __forceinline__ unsigned short f2bf(float f) {
    union { float f; unsigned u; } x; x.f = f;
    return (unsigned short)((x.u + 0x8000u) >> 16);
}

__device__ __forceinline__ void gload_lds16(const unsigned short* g, unsigned short* l) {
    __builtin_amdgcn_global_load_lds(
        (const __attribute__((address_space(1))) unsigned int*)g,
        (__attribute__((address_space(3))) unsigned int*)l, 16, 0, 0);
}

#define SBAR   __builtin_amdgcn_s_barrier()
#define LGKM0  asm volatile("s_waitcnt lgkmcnt(0)" ::: "memory")
#define VMW(n) asm volatile("s_waitcnt vmcnt(" #n ")" ::: "memory")

// ---------------- prep: qkv conv (blocks 0..24575) + W transpose (24576..27647) ----
__global__ __launch_bounds__(256) void prep(
    const float* __restrict__ q, const float* __restrict__ k, const float* __restrict__ v,
    const float* __restrict__ W0, const float* __restrict__ W1, const float* __restrict__ W2,
    unsigned short* __restrict__ qkvbf, unsigned short* __restrict__ Wt)
{
    __shared__ float tile[32][33];
    const int id = blockIdx.x;
    const int t  = threadIdx.x;
    if (id < 24576) {
        const int z  = id >> 13;
        const int xb = id & 8191;
        const float* x = (z == 0) ? q : (z == 1) ? k : v;
        const size_t i = ((size_t)xb * 256 + t) * 4;
        const float4 a = *(const float4*)(x + i);
        ushort4 p = { f2bf(a.x), f2bf(a.y), f2bf(a.z), f2bf(a.w) };
        *(ushort4*)(qkvbf + (size_t)z * 8192 * 1024 + i) = p;
    } else {
        const int idt = id - 24576;
        const int z  = idt >> 10;
        const int r  = idt & 1023;
        const int bx = (r & 31) * 32;
        const int by = (r >> 5) * 32;
        const float* W = (z == 0) ? W0 : (z == 1) ? W1 : W2;
        unsigned short* o = Wt + (size_t)z * 1024 * 1024;
        const int tx = t & 31;
        const int ty = (t >> 5) * 4;
        #pragma unroll
        for (int rr = 0; rr < 4; ++rr)
            tile[ty + rr][tx] = W[(size_t)(by + ty + rr) * 1024 + bx + tx];
        __syncthreads();
        #pragma unroll
        for (int rr = 0; rr < 4; ++rr)
            o[(size_t)(bx + ty + rr) * 1024 + by + tx] = f2bf(tile[tx][ty + rr]);
    }
}

// ======== 2-phase/K-tile, triple-buffered 128x256 GEMM (bf16, K mult of 64) ====
// LDS map (shorts): buf b at b*24576; A-kh at kh*4096 [128][32];
//   B-kh at 8192 + kh*8192 [256][32]. Swizzle: 16B slot s of row r holds
//   global slot s ^ ((r>>1)&3).

#define STAGE_A(bb, kh, tt) do { \
    gload_lds16(gA + (size_t)srowA * lda + (tt) * 64 + (kh) * 32 + scol, \
                lds + (bb) * 24576 + (kh) * 4096 + t512 * 8); \
} while (0)

#define STAGE_B(bb, kh, tt) do { \
    const unsigned short* s_ = gB + (size_t)srowA * ldb + (tt) * 64 + (kh) * 32 + scol; \
    unsigned short* d_ = lds + (bb) * 24576 + 8192 + (kh) * 8192 + t512 * 8; \
    gload_lds16(s_, d_); \
    gload_lds16(s_ + (size_t)128 * ldb, d_ + 4096); \
} while (0)

#define LDSA(bb, kh, i) (*(const short8*)&lds[(bb) * 24576 + (kh) * 4096 + (arow + (i) * 16) * 32 + rslot])
#define LDSB(bb, kh, j) (*(const short8*)&lds[(bb) * 24576 + 8192 + (kh) * 8192 + (brow + (j) * 16) * 32 + rslot])

#define MFMA16 do { \
    __builtin_amdgcn_s_setprio(1); \
    _Pragma("unroll") \
    for (int i_ = 0; i_ < 4; ++i_) \
        _Pragma("unroll") \
        for (int j_ = 0; j_ < 4; ++j_) \
            acc[i_][j_] = __builtin_amdgcn_mfma_f32_16x16x32_bf16( \
                af[i_], bf[j_], acc[i_][j_], 0, 0, 0); \
    __builtin_amdgcn_s_setprio(0); \
} while (0)

__device__ __forceinline__ void gemm3buf(
    const unsigned short* __restrict__ gA, int lda,
    const unsigned short* __restrict__ gB, int ldb,
    int nt, unsigned short* lds, floatx4 (&acc)[4][4])
{
    const int t512 = threadIdx.x;
    const int lane = t512 & 63;
    const int wave = t512 >> 6;
    const int wr   = wave >> 2;          // 0..1 (M)
    const int wc   = wave & 3;           // 0..3 (N)
    const int l15  = lane & 15;
    const int quad = lane >> 4;
    const int srowA = t512 >> 2;                                 // staging row 0..127
    const int scol  = ((t512 & 3) ^ ((t512 >> 3) & 3)) * 8;      // pre-swizzled global slot
    const int rslot = (quad ^ ((l15 >> 1) & 3)) * 8;             // swizzled read slot
    const int arow  = wr * 64 + l15;
    const int brow  = wc * 64 + l15;

    short8 af[4], bf[4];

    // prologue: K-tiles 0 and 1 fully staged (issue order = ledger order)
    STAGE_A(0, 0, 0); STAGE_B(0, 0, 0);
    STAGE_A(0, 1, 0); STAGE_B(0, 1, 0);
    STAGE_A(1, 0, 1); STAGE_B(1, 0, 1);
    STAGE_A(1, 1, 1); STAGE_B(1, 1, 1);
    VMW(9);
    SBAR;

    int b0 = 0, b1 = 1, b2 = 2;
    for (int t = 0; t < nt; ++t) {
        // ---- p0: consume G0(t)={A0,B0} of buf b0; stage G0(t+2) -> buf b2
        #pragma unroll
        for (int j = 0; j < 4; ++j) bf[j] = LDSB(b0, 0, j);
        #pragma unroll
        for (int i = 0; i < 4; ++i) af[i] = LDSA(b0, 0, i);
        if (t + 2 < nt) { STAGE_A(b2, 0, t + 2); STAGE_B(b2, 0, t + 2); }
        SBAR; LGKM0;
        MFMA16;
        if (t < nt - 2)       { VMW(9); }
        else if (t == nt - 2) { VMW(6); }
        else                  { VMW(0); }
        SBAR;
        // ---- p1: consume G1(t)={A1,B1} of buf b0; stage G1(t+2) -> buf b2
        #pragma unroll
        for (int j = 0; j < 4; ++j) bf[j] = LDSB(b0, 1, j);
        #pragma unroll
        for (int i = 0; i < 4; ++i) af[i] = LDSA(b0, 1, i);
        if (t + 2 < nt) { STAGE_A(b2, 1, t + 2); STAGE_B(b2, 1, t + 2); }
        SBAR; LGKM0;
        MFMA16;
        if (t < nt - 1) {
            if (t < nt - 2) { VMW(9); } else { VMW(3); }
            SBAR;
        }
        const int tmp = b0; b0 = b1; b1 = b2; b2 = tmp;
    }
}

#define EPI_IDS                                   \
    const int tt   = threadIdx.x;                 \
    const int lane = tt & 63;                     \
    const int wave = tt >> 6;                     \
    const int wr   = wave >> 2;                   \
    const int wc   = wave & 3;                    \
    const int l15  = lane & 15;                   \
    const int quad = lane >> 4;

// ---------------- fused QKV projection, 768 blocks, XCD-swizzled ----
__global__ __launch_bounds__(512) void proj8(
    const unsigned short* __restrict__ Abf,
    const unsigned short* __restrict__ Wt,
    const float* __restrict__ bq, const float* __restrict__ bk, const float* __restrict__ bv,
    unsigned short* __restrict__ Qp, unsigned short* __restrict__ Kp,
    unsigned short* __restrict__ Vpt)
{
    __shared__ __attribute__((aligned(16))) unsigned short lds[73728];
    const int id = blockIdx.x;
    const int g  = (id & 7) * 96 + (id >> 3);    // 768 = 8 XCDs x 96
    const int z  = g >> 8;                       // 0..2
    const int r  = g & 255;
    const int m0 = (r >> 2) * 128;
    const int n0 = (r & 3) * 256;

    const unsigned short* gA = Abf + (size_t)z * 8192 * 1024 + (size_t)m0 * 1024;
    const unsigned short* gB = Wt  + (size_t)z * 1024 * 1024 + (size_t)n0 * 1024;

    floatx4 acc[4][4] = {};
    gemm3buf(gA, 1024, gB, 1024, 16, lds, acc);

    EPI_IDS
    const float* bias = (z == 0) ? bq : (z == 1) ? bk : bv;
    #pragma unroll
    for (int j = 0; j < 4; ++j) {
        const int col = n0 + wc * 64 + j * 16 + l15;
        const float bv_ = bias[col];
        #pragma unroll
        for (int i = 0; i < 4; ++i) {
            const int row = m0 + wr * 64 + i * 16 + quad * 4;
            if (z < 2) {
                unsigned short* C = (z == 0) ? Qp : Kp;
                #pragma unroll
                for (int r2 = 0; r2 < 4; ++r2)
                    C[(size_t)(row + r2) * 1024 + col] = f2bf(acc[i][j][r2] + bv_);
            } else {
                ushort4 p = { f2bf(acc[i][j][0] + bv_), f2bf(acc[i][j][1] + bv_),
                              f2bf(acc[i][j][2] + bv_), f2bf(acc[i][j][3] + bv_) };
                *(ushort4*)&Vpt[(size_t)col * 8192 + row] = p;
            }
        }
    }
}

// ---------------- scores: Pexp = exp(Qp @ Kp^T / 32) bf16 + row sums ----
__global__ __launch_bounds__(512) void scores8(
    const unsigned short* __restrict__ Qp,
    const unsigned short* __restrict__ Kp,
    unsigned short* __restrict__ Pexp,
    float* __restrict__ rowsum)
{
    __shared__ __attribute__((aligned(16))) unsigned short lds[73728];
    const int id = blockIdx.x;
    const int g  = (id & 7) * 64 + (id >> 3);    // 512 blocks
    const int z  = g >> 7;
    const int r  = g & 127;
    const int m0 = (r >> 3) * 128;
    const int n0 = (r & 7) * 256;

    const unsigned short* gA = Qp + (size_t)z * 2048 * 1024 + (size_t)m0 * 1024;
    const unsigned short* gB = Kp + (size_t)z * 2048 * 1024 + (size_t)n0 * 1024;

    floatx4 acc[4][4] = {};
    gemm3buf(gA, 1024, gB, 1024, 16, lds, acc);

    EPI_IDS
    unsigned short* P = Pexp + (size_t)z * 2048 * 2048;
    float* rs = rowsum + (size_t)z * 2048;
    #pragma unroll
    for (int i = 0; i < 4; ++i) {
        const int rowb = m0 + wr * 64 + i * 16 + quad * 4;
        float sm[4] = {0.f, 0.f, 0.f, 0.f};
        #pragma unroll
        for (int j = 0; j < 4; ++j) {
            const int col = n0 + wc * 64 + j * 16 + l15;
            #pragma unroll
            for (int r2 = 0; r2 < 4; ++r2) {
                const float p = __expf(acc[i][j][r2] * 0.03125f);
                sm[r2] += p;
                P[(size_t)(rowb + r2) * 2048 + col] = f2bf(p);
            }
        }
        #pragma unroll
        for (int r2 = 0; r2 < 4; ++r2) {
            float s = sm[r2];
            s += __shfl_xor(s, 1);
            s += __shfl_xor(s, 2);
            s += __shfl_xor(s, 4);
            s += __shfl_xor(s, 8);
            if (l15 == 0)
                atomicAdd(&rs[rowb + r2], s);
        }
    }
}

// ---------------- PV: out = (Pexp @ Vpt^T) / rowsum, fp32 ----------------
__global__ __launch_bounds__(512) void pv8(
    const unsigned short* __restrict__ Pexp,
    const unsigned short* __restrict__ Vpt,
    const float* __restrict__ rowsum,
    float* __restrict__ out)
{
    __shared__ __attribute__((aligned(16))) unsigned short lds[73728];
    const int id = blockIdx.x;
    const int g  = (id & 7) * 32 + (id >> 3);    // 256 blocks
    const int z  = g >> 6;
    const int r  = g & 63;
    const int m0 = (r >> 2) * 128;
    const int n0 = (r & 3) * 256;

    const unsigned short* gA = Pexp + (size_t)z * 2048 * 2048 + (size_t)m0 * 2048;
    const unsigned short* gB = Vpt  + (size_t)n0 * 8192 + (size_t)z * 2048;

    floatx4 acc[4][4] = {};
    gemm3buf(gA, 2048, gB, 8192, 32, lds, acc);

    EPI_IDS
    const float* rs = rowsum + (size_t)z * 2048;
    float* C = out + (size_t)z * 2048 * 1024;
    #pragma unroll
    for (int i = 0; i < 4; ++i) {
        const int rowb = m0 + wr * 64 + i * 16 + quad * 4;
        float inv[4];
        #pragma unroll
        for (int r2 = 0; r2 < 4; ++r2) inv[r2] = 1.0f / rs[rowb + r2];
        #pragma unroll
        for (int j = 0; j < 4; ++j) {
            const int col = n0 + wc * 64 + j * 16 + l15;
            #pragma unroll
            for (int r2 = 0; r2 < 4; ++r2)
                C[(size_t)(rowb + r2) * 1024 + col] = acc[i][j][r2] * inv[r2];
        }
    }
}

extern "C" void kernel_launch(void* const* d_in, const int* in_sizes, int n_in,
                              void* d_out, int out_size, void* d_ws, size_t ws_size,
                              hipStream_t stream)
{
    const float* q  = (const float*)d_in[0];
    const float* k  = (const float*)d_in[1];
    const float* v  = (const float*)d_in[2];
    const float* Wq = (const float*)d_in[3];
    const float* bq = (const float*)d_in[4];
    const float* Wk = (const float*)d_in[5];
    const float* bk = (const float*)d_in[6];
    const float* Wv = (const float*)d_in[7];
    const float* bv = (const float*)d_in[8];
    float* out = (float*)d_out;

    const int Bn = 4, S = 2048;

    char* w = (char*)d_ws;
    unsigned short* Wt     = (unsigned short*)(w);                  // 6 MB
    unsigned short* Qp     = (unsigned short*)(w + (6u << 20));     // 16 MB [8192,1024]
    unsigned short* Kp     = (unsigned short*)(w + (22u << 20));    // 16 MB
    unsigned short* Vpt    = (unsigned short*)(w + (38u << 20));    // 16 MB [1024,8192]
    unsigned short* qkvbf  = (unsigned short*)(w + (54u << 20));    // 48 MB (dead after proj)
    unsigned short* Pexp   = (unsigned short*)(w + (54u << 20));    // 32 MB (over dead qkvbf)
    float*          rowsum = (float*)(w + (86u << 20));             // 32 KB

    // zero the row-sum accumulators (ws is poisoned before each call)
    hipMemsetAsync(rowsum, 0, (size_t)Bn * S * sizeof(float), stream);

    // prep: qkv fp32->bf16 + W->W^T bf16
    prep<<<dim3(27648), dim3(256), 0, stream>>>(q, k, v, Wq, Wk, Wv, qkvbf, Wt);

    // fused projections (3-buf 128x256): -> Qp, Kp, Vpt^T
    proj8<<<dim3(768), dim3(512), 0, stream>>>(qkvbf, Wt, bq, bk, bv, Qp, Kp, Vpt);

    // Pexp = exp(Qp @ Kp^T / 32) bf16 + rowsum atomics
    scores8<<<dim3(512), dim3(512), 0, stream>>>(Qp, Kp, Pexp, rowsum);

    // out = (Pexp @ Vpt^T) / rowsum
    pv8<<<dim3(256), dim3(512), 0, stream>>>(Pexp, Vpt, rowsum, out);
}